// Round 6
// baseline (85.796 us; speedup 1.0000x reference)
//
#include <hip/hip_runtime.h>
#include <cstddef>

#define NB 128   // #molecules / tokens; grid size (<=256 CUs -> co-resident)

// bf16 helpers: RNE pack; packed layout low-ushort = even element
__device__ __forceinline__ unsigned int f2bf(float x) {
  unsigned int u = __float_as_uint(x);
  u = (u + 0x7FFFu + ((u >> 16) & 1u)) >> 16;
  return u;
}
__device__ __forceinline__ float bf_lo(unsigned int w) { return __uint_as_float(w << 16); }
__device__ __forceinline__ float bf_hi(unsigned int w) { return __uint_as_float(w & 0xFFFF0000u); }

__global__ void init_kernel(int* cnt) {
  if (threadIdx.x < 16) cnt[threadIdx.x] = 0;
}

// light grid barrier: release-add, RELAXED poll (no cache inv per poll),
// single acquire at exit.  Counters zeroed per call by init_kernel.
__device__ __forceinline__ void gridbar(int* c) {
  __syncthreads();
  if (threadIdx.x == 0) {
    __hip_atomic_fetch_add(c, 1, __ATOMIC_RELEASE, __HIP_MEMORY_SCOPE_AGENT);
    while (__hip_atomic_load(c, __ATOMIC_RELAXED, __HIP_MEMORY_SCOPE_AGENT) < NB)
      __builtin_amdgcn_s_sleep(4);
    (void)__hip_atomic_load(c, __ATOMIC_ACQUIRE, __HIP_MEMORY_SCOPE_AGENT);
  }
  __syncthreads();
}

// ======================================================================
// ONE fused kernel: weight-convert prologue + GNN + 2 transformer layers
// + head.  grid=128, block=512, 2 software grid barriers.
// ======================================================================
__global__ __launch_bounds__(512, 1) void fused_kernel(
    const int* __restrict__ fp, const float* __restrict__ Aadj,
    const float* __restrict__ embed, const float* __restrict__ Wfp,
    const float* __restrict__ bfp, const float* __restrict__ fc_w,
    const float* __restrict__ fc_b,
    const float* __restrict__ qkv_w, const float* __restrict__ qkv_b,
    const float* __restrict__ out_w, const float* __restrict__ out_b,
    const float* __restrict__ ln1_s, const float* __restrict__ ln1_b,
    const float* __restrict__ ff1_w, const float* __restrict__ ff1_b,
    const float* __restrict__ ff2_w, const float* __restrict__ ff2_b,
    const float* __restrict__ ln2_s, const float* __restrict__ ln2_b,
    const float* __restrict__ Wout_w, const float* __restrict__ Wout_b,
    const float* __restrict__ Wprop_w, const float* __restrict__ Wprop_b,
    float* __restrict__ qq0, float* __restrict__ qq1,
    unsigned short* __restrict__ wT1b, unsigned short* __restrict__ w2b,
    int* __restrict__ cnt, float* __restrict__ out)
{
  __shared__ __align__(16) float xT[64 * 68];    // GNN xT; later re-carved
  __shared__ __align__(16) float hR[64 * 68];
  __shared__ __align__(16) float WT[64 * 68];
  __shared__ __align__(16) float Ablk[64 * 64];
  __shared__ float prt[64 * 17];
  __shared__ float inv64[64];
  __shared__ __align__(16) float red[512];
  __shared__ __align__(16) float mol[64];
  __shared__ __align__(16) float vloc[64];
  __shared__ __align__(16) float vloc2[64];
  __shared__ float wred[8];

  const int b   = blockIdx.x;
  const int tid = threadIdx.x;

  // ============ prologue: bf16 weight conversion (this block's share) ====
  {
    const int lc = b >> 6, j0 = (b & 63) * 32;
    if (tid < 256) {           // stage 32 j-rows of ff1_w into LDS
      int jr = tid >> 3, kq = tid & 7;
      const float* src = ff1_w + (size_t)lc * 131072 + (size_t)(j0 + jr) * 64 + kq * 8;
      *(float4*)&hR[jr * 68 + kq * 8]     = *(const float4*)src;
      *(float4*)&hR[jr * 68 + kq * 8 + 4] = *(const float4*)(src + 4);
    } else {                   // straight bf16 convert of ff2_w chunk
      int t2 = tid - 256;
      const float* s = ff2_w + (size_t)b * 2048 + t2 * 8;
      float4 v0 = *(const float4*)s, v1 = *(const float4*)(s + 4);
      uint4 o;
      o.x = f2bf(v0.x) | (f2bf(v0.y) << 16);
      o.y = f2bf(v0.z) | (f2bf(v0.w) << 16);
      o.z = f2bf(v1.x) | (f2bf(v1.y) << 16);
      o.w = f2bf(v1.z) | (f2bf(v1.w) << 16);
      *(uint4*)(w2b + (size_t)b * 2048 + t2 * 8) = o;
    }
    __syncthreads();
    if (tid < 256) {           // write transposed bf16: wT1b[l][k][j]
      int k = tid >> 2, jq = (tid & 3) * 8;
      uint4 o;
      o.x = f2bf(hR[(jq + 0) * 68 + k]) | (f2bf(hR[(jq + 1) * 68 + k]) << 16);
      o.y = f2bf(hR[(jq + 2) * 68 + k]) | (f2bf(hR[(jq + 3) * 68 + k]) << 16);
      o.z = f2bf(hR[(jq + 4) * 68 + k]) | (f2bf(hR[(jq + 5) * 68 + k]) << 16);
      o.w = f2bf(hR[(jq + 6) * 68 + k]) | (f2bf(hR[(jq + 7) * 68 + k]) << 16);
      *(uint4*)(wT1b + (size_t)lc * 131072 + (size_t)k * 2048 + j0 + jq) = o;
    }
  }

  // ============ GNN phase (256 compute threads; all hit the syncs) ======
  for (int idx = tid; idx < 4096; idx += 512) {
    int r = idx >> 6, c = idx & 63;
    xT[c * 68 + r] = embed[(size_t)fp[b * 64 + r] * 64 + c];
  }
  for (int idx = tid; idx < 1024; idx += 512) {
    int r = idx >> 4, q = idx & 15;
    *(float4*)&Ablk[r * 64 + q * 4] =
        *(const float4*)(Aadj + (size_t)(b * 64 + r) * 8192 + b * 64 + q * 4);
  }

  const int rg = tid & 15, cg = (tid >> 4) & 15;
  const int r0 = rg * 4,   c0g = cg * 4;

  for (int l = 0; l < 3; ++l) {
    for (int idx = tid; idx < 4096; idx += 512) {
      int o = idx >> 6, k = idx & 63;
      WT[k * 68 + o] = Wfp[l * 4096 + o * 64 + k];
    }
    __syncthreads();

    float4 acc0, acc1, acc2, acc3;
    if (tid < 256) {
      float4 bb = *(const float4*)&bfp[l * 64 + c0g];
      acc0 = bb; acc1 = bb; acc2 = bb; acc3 = bb;
#pragma unroll 8
      for (int k = 0; k < 64; ++k) {
        float4 xv = *(const float4*)&xT[k * 68 + r0];
        float4 wv = *(const float4*)&WT[k * 68 + c0g];
        acc0.x += xv.x * wv.x; acc0.y += xv.x * wv.y; acc0.z += xv.x * wv.z; acc0.w += xv.x * wv.w;
        acc1.x += xv.y * wv.x; acc1.y += xv.y * wv.y; acc1.z += xv.y * wv.z; acc1.w += xv.y * wv.w;
        acc2.x += xv.z * wv.x; acc2.y += xv.z * wv.y; acc2.z += xv.z * wv.z; acc2.w += xv.z * wv.w;
        acc3.x += xv.w * wv.x; acc3.y += xv.w * wv.y; acc3.z += xv.w * wv.z; acc3.w += xv.w * wv.w;
      }
      acc0.x = fmaxf(acc0.x, 0.f); acc0.y = fmaxf(acc0.y, 0.f); acc0.z = fmaxf(acc0.z, 0.f); acc0.w = fmaxf(acc0.w, 0.f);
      acc1.x = fmaxf(acc1.x, 0.f); acc1.y = fmaxf(acc1.y, 0.f); acc1.z = fmaxf(acc1.z, 0.f); acc1.w = fmaxf(acc1.w, 0.f);
      acc2.x = fmaxf(acc2.x, 0.f); acc2.y = fmaxf(acc2.y, 0.f); acc2.z = fmaxf(acc2.z, 0.f); acc2.w = fmaxf(acc2.w, 0.f);
      acc3.x = fmaxf(acc3.x, 0.f); acc3.y = fmaxf(acc3.y, 0.f); acc3.z = fmaxf(acc3.z, 0.f); acc3.w = fmaxf(acc3.w, 0.f);
      *(float4*)&hR[(r0 + 0) * 68 + c0g] = acc0;
      *(float4*)&hR[(r0 + 1) * 68 + c0g] = acc1;
      *(float4*)&hR[(r0 + 2) * 68 + c0g] = acc2;
      *(float4*)&hR[(r0 + 3) * 68 + c0g] = acc3;
    }
    __syncthreads();

    if (tid < 256) {
#pragma unroll 8
      for (int j = 0; j < 64; ++j) {
        float4 av = *(const float4*)&Ablk[j * 64 + r0];   // A symmetric
        float4 hv = *(const float4*)&hR[j * 68 + c0g];
        acc0.x += av.x * hv.x; acc0.y += av.x * hv.y; acc0.z += av.x * hv.z; acc0.w += av.x * hv.w;
        acc1.x += av.y * hv.x; acc1.y += av.y * hv.y; acc1.z += av.y * hv.z; acc1.w += av.y * hv.w;
        acc2.x += av.z * hv.x; acc2.y += av.z * hv.y; acc2.z += av.z * hv.z; acc2.w += av.z * hv.w;
        acc3.x += av.w * hv.x; acc3.y += av.w * hv.y; acc3.z += av.w * hv.z; acc3.w += av.w * hv.w;
      }
      prt[(r0 + 0) * 17 + cg] = acc0.x*acc0.x + acc0.y*acc0.y + acc0.z*acc0.z + acc0.w*acc0.w;
      prt[(r0 + 1) * 17 + cg] = acc1.x*acc1.x + acc1.y*acc1.y + acc1.z*acc1.z + acc1.w*acc1.w;
      prt[(r0 + 2) * 17 + cg] = acc2.x*acc2.x + acc2.y*acc2.y + acc2.z*acc2.z + acc2.w*acc2.w;
      prt[(r0 + 3) * 17 + cg] = acc3.x*acc3.x + acc3.y*acc3.y + acc3.z*acc3.z + acc3.w*acc3.w;
    }
    __syncthreads();
    if (tid < 64) {
      float s = 0.f;
#pragma unroll
      for (int t = 0; t < 16; ++t) s += prt[tid * 17 + t];
      inv64[tid] = 1.0f / fmaxf(sqrtf(s), 1e-12f);
    }
    __syncthreads();
    if (tid < 256) {
      float i0 = inv64[r0 + 0], i1 = inv64[r0 + 1];
      float i2 = inv64[r0 + 2], i3 = inv64[r0 + 3];
      float4 w0 = {acc0.x * i0, acc1.x * i1, acc2.x * i2, acc3.x * i3};
      float4 w1 = {acc0.y * i0, acc1.y * i1, acc2.y * i2, acc3.y * i3};
      float4 w2 = {acc0.z * i0, acc1.z * i1, acc2.z * i2, acc3.z * i3};
      float4 w3 = {acc0.w * i0, acc1.w * i1, acc2.w * i2, acc3.w * i3};
      *(float4*)&xT[(c0g + 0) * 68 + r0] = w0;
      *(float4*)&xT[(c0g + 1) * 68 + r0] = w1;
      *(float4*)&xT[(c0g + 2) * 68 + r0] = w2;
      *(float4*)&xT[(c0g + 3) * 68 + r0] = w3;
    }
    __syncthreads();
  }

  // pool (512-wide) + fc (512-wide shuffle-8)
  {
    int k = tid & 63, half = tid >> 6;          // 8 halves x 8 atoms
    const float* xp = &xT[k * 68 + half * 8];
    float s = 0.f;
#pragma unroll
    for (int i = 0; i < 8; ++i) s += xp[i];
    red[half * 64 + k] = s;
  }
  __syncthreads();
  if (tid < 64) {
    float m = 0.f;
#pragma unroll
    for (int p = 0; p < 8; ++p) m += red[p * 64 + tid];
    mol[tid] = m;
  }
  __syncthreads();
  {
    int d = tid >> 3, c0 = (tid & 7) * 8;
    const float* wr = fc_w + d * 64 + c0;
    float p = 0.f;
#pragma unroll
    for (int i = 0; i < 8; ++i) p += mol[c0 + i] * wr[i];
    p += __shfl_xor(p, 1); p += __shfl_xor(p, 2); p += __shfl_xor(p, 4);
    if ((tid & 7) == 0) vloc[d] = p + fc_b[d];
  }
  __syncthreads();

  // ============ transformer phase: LDS re-carve over xT =================
  float* qown = xT;          // [64]
  float* Pl   = xT + 64;     // [4*132]
  float* cb   = xT + 592;    // [2048]
  float* redt = xT + 2640;   // [512]
  float* osh  = xT + 3152;   // [64]
  float* rres = xT + 3216;   // [64]
  float* ffp  = xT + 3280;   // [64]

  // layer-0 qkv (384-wide, shuffle-2), then grid barrier
  if (tid < 384) {
    int o = tid >> 1, c0 = (tid & 1) * 32;
    const float4* wr = (const float4*)(qkv_w + o * 64 + c0);
    float p = 0.f;
#pragma unroll
    for (int k4 = 0; k4 < 8; ++k4) {
      float4 w4 = wr[k4];
      float4 x4 = *(const float4*)&vloc[c0 + k4 * 4];
      p += w4.x * x4.x + w4.y * x4.y + w4.z * x4.z + w4.w * x4.w;
    }
    p += __shfl_xor(p, 1);
    if ((tid & 1) == 0) {
      float a = p + qkv_b[o];
      qq0[(size_t)b * 192 + o] = a;
      if (o < 64) qown[o] = a;
    }
  }
  gridbar(cnt);

  for (int l = 0; l < 2; ++l) {
    const float* qq_in = l ? qq1 : qq0;
    const float* ow    = out_w + (size_t)l * 4096;
    const float* obp   = out_b + l * 64;
    const float* l1s   = ln1_s + l * 64;
    const float* l1b   = ln1_b + l * 64;
    const float* l2s   = ln2_s + l * 64;
    const float* l2b   = ln2_b + l * 64;
    const unsigned short* w1p = wT1b + (size_t)l * 131072;
    const unsigned short* w2p = w2b  + (size_t)l * 131072;
    const float* f1b = ff1_b + l * 2048;
    const float* f2b = ff2_b + l * 64;

    // ---- scores + softmax (no-max: scores are tiny) ----
    {
      const int j = tid & 127, h = tid >> 7;
      const float4* qp = (const float4*)&qown[h * 16];
      const float4* kp = (const float4*)(qq_in + (size_t)j * 192 + 64 + h * 16);
      float s = 0.f;
#pragma unroll
      for (int t = 0; t < 4; ++t) {
        float4 a4 = qp[t], b4 = kp[t];
        s += a4.x * b4.x + a4.y * b4.y + a4.z * b4.z + a4.w * b4.w;
      }
      float e = expf(s * 0.25f);
      float sm = e;
      for (int off = 32; off; off >>= 1) sm += __shfl_xor(sm, off);
      if ((tid & 63) == 0) wred[tid >> 6] = sm;
      __syncthreads();
      Pl[h * 132 + j] = e / (wred[2 * h] + wred[2 * h + 1]);
    }
    __syncthreads();

    // ---- PV ----
    {
      const int d = tid & 63, part = tid >> 6, h2 = d >> 4;
      float a = 0.f;
#pragma unroll
      for (int jj = 0; jj < 16; ++jj) {
        int j2 = part * 16 + jj;
        a += Pl[h2 * 132 + j2] * qq_in[(size_t)j2 * 192 + 128 + d];
      }
      redt[part * 64 + d] = a;
    }
    __syncthreads();
    if (tid < 64) {
      float o = 0.f;
#pragma unroll
      for (int p = 0; p < 8; ++p) o += redt[p * 64 + tid];
      osh[tid] = o;
    }
    __syncthreads();

    // ---- out-proj (512-wide, coalesced, shuffle-8) ----
    {
      int d = tid >> 3, c0 = (tid & 7) * 8;
      const float* wr = ow + d * 64 + c0;
      float p = 0.f;
#pragma unroll
      for (int i = 0; i < 8; ++i) p += osh[c0 + i] * wr[i];
      p += __shfl_xor(p, 1); p += __shfl_xor(p, 2); p += __shfl_xor(p, 4);
      if ((tid & 7) == 0) rres[d] = p;
    }
    __syncthreads();

    // ---- residual + LN1 ----
    if (tid < 64) {
      const int d = tid;
      float r = vloc[d] + rres[d] + obp[d];
      float mu = r;
      for (int off = 32; off; off >>= 1) mu += __shfl_xor(mu, off);
      mu *= (1.0f / 64.0f);
      float df = r - mu;
      float var = df * df;
      for (int off = 32; off; off >>= 1) var += __shfl_xor(var, off);
      var *= (1.0f / 64.0f);
      vloc2[d] = df / sqrtf(var + 1e-5f) * l1s[d] + l1b[d];
    }
    __syncthreads();

    // ---- FF1: bf16 transposed w1, coalesced ----
    {
      const uint2* wt = (const uint2*)w1p;
      float4 a0 = {0.f, 0.f, 0.f, 0.f}, a1 = {0.f, 0.f, 0.f, 0.f};
#pragma unroll 8
      for (int k = 0; k < 64; k += 2) {
        float v0 = vloc2[k], v1 = vloc2[k + 1];
        uint2 w0 = wt[(size_t)k * 512 + tid];
        uint2 w1v = wt[(size_t)(k + 1) * 512 + tid];
        a0.x += v0 * bf_lo(w0.x); a0.y += v0 * bf_hi(w0.x);
        a0.z += v0 * bf_lo(w0.y); a0.w += v0 * bf_hi(w0.y);
        a1.x += v1 * bf_lo(w1v.x); a1.y += v1 * bf_hi(w1v.x);
        a1.z += v1 * bf_lo(w1v.y); a1.w += v1 * bf_hi(w1v.y);
      }
      const int j0 = tid * 4;
      float4 bb = *(const float4*)&f1b[j0];
      float4 r;
      r.x = fmaxf(a0.x + a1.x + bb.x, 0.f);
      r.y = fmaxf(a0.y + a1.y + bb.y, 0.f);
      r.z = fmaxf(a0.z + a1.z + bb.z, 0.f);
      r.w = fmaxf(a0.w + a1.w + bb.w, 0.f);
      *(float4*)&cb[j0] = r;
    }
    __syncthreads();

    // ---- FF2: bf16 w2, wave owns 8 rows ----
    {
      const int w = tid >> 6, lane = tid & 63;
      const uint4* w2f = (const uint4*)w2p;
      const float4* cbf = (const float4*)cb;
#pragma unroll
      for (int rr = 0; rr < 8; ++rr) {
        int d = w * 8 + rr;
        float p = 0.f;
#pragma unroll
        for (int it = 0; it < 4; ++it) {
          int fb = it * 64 + lane;
          uint4 wv = w2f[(size_t)d * 256 + fb];
          float4 c0v = cbf[fb * 2], c1v = cbf[fb * 2 + 1];
          p += bf_lo(wv.x) * c0v.x + bf_hi(wv.x) * c0v.y
             + bf_lo(wv.y) * c0v.z + bf_hi(wv.y) * c0v.w
             + bf_lo(wv.z) * c1v.x + bf_hi(wv.z) * c1v.y
             + bf_lo(wv.w) * c1v.z + bf_hi(wv.w) * c1v.w;
        }
        for (int off = 32; off; off >>= 1) p += __shfl_xor(p, off);
        if (lane == 0) ffp[d] = p;
      }
    }
    __syncthreads();

    // ---- residual + LN2 -> vloc ----
    if (tid < 64) {
      const int d = tid;
      float r = vloc2[d] + ffp[d] + f2b[d];
      float mu = r;
      for (int off = 32; off; off >>= 1) mu += __shfl_xor(mu, off);
      mu *= (1.0f / 64.0f);
      float df = r - mu;
      float var = df * df;
      for (int off = 32; off; off >>= 1) var += __shfl_xor(var, off);
      var *= (1.0f / 64.0f);
      vloc[d] = df / sqrtf(var + 1e-5f) * l2s[d] + l2b[d];
    }
    __syncthreads();

    if (l == 0) {
      // next-layer qkv (384-wide), then barrier 2
      if (tid < 384) {
        int o = tid >> 1, c0 = (tid & 1) * 32;
        const float4* wr = (const float4*)(qkv_w + 12288 + o * 64 + c0);
        float p = 0.f;
#pragma unroll
        for (int k4 = 0; k4 < 8; ++k4) {
          float4 w4 = wr[k4];
          float4 x4 = *(const float4*)&vloc[c0 + k4 * 4];
          p += w4.x * x4.x + w4.y * x4.y + w4.z * x4.z + w4.w * x4.w;
        }
        p += __shfl_xor(p, 1);
        if ((tid & 1) == 0) {
          float a = p + qkv_b[192 + o];
          qq1[(size_t)b * 192 + o] = a;
          if (o < 64) qown[o] = a;
        }
      }
      gridbar(cnt + 1);
    }
  }

  // ============ output head ============
  {
    int d = tid >> 3, c0 = (tid & 7) * 8;
    const float* wr = Wout_w + d * 64 + c0;
    float p = 0.f;
#pragma unroll
    for (int i = 0; i < 8; ++i) p += vloc[c0 + i] * wr[i];
    p += __shfl_xor(p, 1); p += __shfl_xor(p, 2); p += __shfl_xor(p, 4);
    if ((tid & 7) == 0) redt[d] = fmaxf(p + Wout_b[d], 0.f);
  }
  __syncthreads();
  {
    int d = tid >> 3, c0 = (tid & 7) * 8;
    const float* wr = Wout_w + 4096 + d * 64 + c0;
    float p = 0.f;
#pragma unroll
    for (int i = 0; i < 8; ++i) p += redt[c0 + i] * wr[i];
    p += __shfl_xor(p, 1); p += __shfl_xor(p, 2); p += __shfl_xor(p, 4);
    if ((tid & 7) == 0) redt[64 + d] = fmaxf(p + Wout_b[64 + d], 0.f);
  }
  __syncthreads();
  if (tid < 2) {
    float a = Wprop_b[tid];
    const float* wr = Wprop_w + tid * 64;
#pragma unroll 8
    for (int c = 0; c < 64; ++c) a += redt[64 + c] * wr[c];
    out[b * 2 + tid] = a;
  }
}

// ======================================================================
extern "C" void kernel_launch(void* const* d_in, const int* in_sizes, int n_in,
                              void* d_out, int out_size, void* d_ws, size_t ws_size,
                              hipStream_t stream) {
  const int*   fp      = (const int*)  d_in[0];
  const float* Aadj    = (const float*)d_in[1];
  const float* embed   = (const float*)d_in[2];
  const float* Wfp     = (const float*)d_in[3];
  const float* bfp     = (const float*)d_in[4];
  const float* fc_w    = (const float*)d_in[5];
  const float* fc_b    = (const float*)d_in[6];
  const float* qkv_w   = (const float*)d_in[7];
  const float* qkv_b   = (const float*)d_in[8];
  const float* out_w   = (const float*)d_in[9];
  const float* out_b   = (const float*)d_in[10];
  const float* ln1_s   = (const float*)d_in[11];
  const float* ln1_b   = (const float*)d_in[12];
  const float* ff1_w   = (const float*)d_in[13];
  const float* ff1_b   = (const float*)d_in[14];
  const float* ff2_w   = (const float*)d_in[15];
  const float* ff2_b   = (const float*)d_in[16];
  const float* ln2_s   = (const float*)d_in[17];
  const float* ln2_b   = (const float*)d_in[18];
  const float* Wout_w  = (const float*)d_in[19];
  const float* Wout_b  = (const float*)d_in[20];
  const float* Wprop_w = (const float*)d_in[21];
  const float* Wprop_b = (const float*)d_in[22];
  float* out = (float*)d_out;

  float* ws  = (float*)d_ws;
  int*   cnt = (int*)ws;                    // 16 ints
  float* qq0 = ws + 64;                     // [128][192]
  float* qq1 = ws + 64 + 24576;             // [128][192]
  unsigned short* wT1b = (unsigned short*)(ws + 64 + 49152);  // 2x[64][2048]
  unsigned short* w2b  = wT1b + 262144;                       // 2x[64][2048]

  init_kernel<<<dim3(1), dim3(64), 0, stream>>>(cnt);
  fused_kernel<<<dim3(NB), dim3(512), 0, stream>>>(
      fp, Aadj, embed, Wfp, bfp, fc_w, fc_b,
      qkv_w, qkv_b, out_w, out_b, ln1_s, ln1_b,
      ff1_w, ff1_b, ff2_w, ff2_b, ln2_s, ln2_b,
      Wout_w, Wout_b, Wprop_w, Wprop_b,
      qq0, qq1, wT1b, w2b, cnt, out);
}

// Round 7
// 64.435 us; speedup vs baseline: 1.3315x; 1.3315x over previous
//
#include <hip/hip_runtime.h>
#include <cstddef>

#define NB 128   // #molecules / tokens

// ======================================================================
// K1: blocks 0..127: GNN + pool + fc + qkv(layer0).  blocks 128..191:
// transpose ff1_w -> wT1 (f32, k-major) on otherwise-idle CUs.  block=256.
// ======================================================================
__global__ __launch_bounds__(256) void gnn_kernel(
    const int* __restrict__ fp, const float* __restrict__ Aadj,
    const float* __restrict__ embed, const float* __restrict__ Wfp,
    const float* __restrict__ bfp, const float* __restrict__ fc_w,
    const float* __restrict__ fc_b,
    const float* __restrict__ qkv_w, const float* __restrict__ qkv_b,
    const float* __restrict__ ff1_w, float* __restrict__ wT1,
    float* __restrict__ vout, float* __restrict__ qqout)
{
  __shared__ __align__(16) float xT[64 * 68];    // [feat k][atom]
  __shared__ __align__(16) float hR[64 * 68];    // [atom][feat]
  __shared__ __align__(16) float WT[64 * 68];    // [k][o]  (W transposed)
  __shared__ __align__(16) float Ablk[64 * 64];  // [i][j] symmetric
  __shared__ float prt[64 * 17];
  __shared__ float inv64[64];
  __shared__ float red[256];
  __shared__ __align__(16) float mol[64];
  __shared__ __align__(16) float vloc[64];

  const int bid = blockIdx.x;
  const int tid = threadIdx.x;

  // ---------------- transpose blocks ----------------
  if (bid >= NB) {
    const int t = bid - NB;            // 0..63
    const int l = t >> 5, j0 = (t & 31) * 64;
    const float* src = ff1_w + (size_t)l * 131072;
    float*       dst = wT1  + (size_t)l * 131072;
#pragma unroll
    for (int q = 0; q < 4; ++q) {      // read coalesced rows j
      int jr = (tid >> 4) + 16 * q, kq = tid & 15;
      float4 vv = *(const float4*)(src + (size_t)(j0 + jr) * 64 + kq * 4);
      *(float4*)&xT[jr * 68 + kq * 4] = vv;
    }
    __syncthreads();
#pragma unroll
    for (int q = 0; q < 4; ++q) {      // write coalesced rows k
      int kr = (tid >> 4) + 16 * q, jq = tid & 15;
      float4 ov;
      ov.x = xT[(jq * 4 + 0) * 68 + kr];
      ov.y = xT[(jq * 4 + 1) * 68 + kr];
      ov.z = xT[(jq * 4 + 2) * 68 + kr];
      ov.w = xT[(jq * 4 + 3) * 68 + kr];
      *(float4*)(dst + (size_t)kr * 2048 + j0 + jq * 4) = ov;
    }
    return;
  }

  // ---------------- GNN blocks ----------------
  const int b  = bid;
  const int rg = tid & 15, cg = tid >> 4;   // 16 row-groups x 16 col-groups
  const int r0 = rg * 4,   c0 = cg * 4;

  for (int idx = tid; idx < 4096; idx += 256) {
    int r = idx >> 6, c = idx & 63;
    xT[c * 68 + r] = embed[(size_t)fp[b * 64 + r] * 64 + c];
  }
  for (int idx = tid; idx < 1024; idx += 256) {
    int r = idx >> 4, q = idx & 15;
    *(float4*)&Ablk[r * 64 + q * 4] =
        *(const float4*)(Aadj + (size_t)(b * 64 + r) * 8192 + b * 64 + q * 4);
  }

  for (int l = 0; l < 3; ++l) {
    for (int idx = tid; idx < 4096; idx += 256) {
      int o = idx >> 6, k = idx & 63;
      WT[k * 68 + o] = Wfp[l * 4096 + o * 64 + k];
    }
    __syncthreads();

    float4 bb = *(const float4*)&bfp[l * 64 + c0];
    float4 acc0 = bb, acc1 = bb, acc2 = bb, acc3 = bb;
#pragma unroll 8
    for (int k = 0; k < 64; ++k) {
      float4 xv = *(const float4*)&xT[k * 68 + r0];
      float4 wv = *(const float4*)&WT[k * 68 + c0];
      acc0.x += xv.x * wv.x; acc0.y += xv.x * wv.y; acc0.z += xv.x * wv.z; acc0.w += xv.x * wv.w;
      acc1.x += xv.y * wv.x; acc1.y += xv.y * wv.y; acc1.z += xv.y * wv.z; acc1.w += xv.y * wv.w;
      acc2.x += xv.z * wv.x; acc2.y += xv.z * wv.y; acc2.z += xv.z * wv.z; acc2.w += xv.z * wv.w;
      acc3.x += xv.w * wv.x; acc3.y += xv.w * wv.y; acc3.z += xv.w * wv.z; acc3.w += xv.w * wv.w;
    }
    acc0.x = fmaxf(acc0.x, 0.f); acc0.y = fmaxf(acc0.y, 0.f); acc0.z = fmaxf(acc0.z, 0.f); acc0.w = fmaxf(acc0.w, 0.f);
    acc1.x = fmaxf(acc1.x, 0.f); acc1.y = fmaxf(acc1.y, 0.f); acc1.z = fmaxf(acc1.z, 0.f); acc1.w = fmaxf(acc1.w, 0.f);
    acc2.x = fmaxf(acc2.x, 0.f); acc2.y = fmaxf(acc2.y, 0.f); acc2.z = fmaxf(acc2.z, 0.f); acc2.w = fmaxf(acc2.w, 0.f);
    acc3.x = fmaxf(acc3.x, 0.f); acc3.y = fmaxf(acc3.y, 0.f); acc3.z = fmaxf(acc3.z, 0.f); acc3.w = fmaxf(acc3.w, 0.f);
    *(float4*)&hR[(r0 + 0) * 68 + c0] = acc0;
    *(float4*)&hR[(r0 + 1) * 68 + c0] = acc1;
    *(float4*)&hR[(r0 + 2) * 68 + c0] = acc2;
    *(float4*)&hR[(r0 + 3) * 68 + c0] = acc3;
    __syncthreads();

#pragma unroll 8
    for (int j = 0; j < 64; ++j) {
      float4 av = *(const float4*)&Ablk[j * 64 + r0];   // A sym: = A[r0..][j]
      float4 hv = *(const float4*)&hR[j * 68 + c0];
      acc0.x += av.x * hv.x; acc0.y += av.x * hv.y; acc0.z += av.x * hv.z; acc0.w += av.x * hv.w;
      acc1.x += av.y * hv.x; acc1.y += av.y * hv.y; acc1.z += av.y * hv.z; acc1.w += av.y * hv.w;
      acc2.x += av.z * hv.x; acc2.y += av.z * hv.y; acc2.z += av.z * hv.z; acc2.w += av.z * hv.w;
      acc3.x += av.w * hv.x; acc3.y += av.w * hv.y; acc3.z += av.w * hv.z; acc3.w += av.w * hv.w;
    }

    prt[(r0 + 0) * 17 + cg] = acc0.x*acc0.x + acc0.y*acc0.y + acc0.z*acc0.z + acc0.w*acc0.w;
    prt[(r0 + 1) * 17 + cg] = acc1.x*acc1.x + acc1.y*acc1.y + acc1.z*acc1.z + acc1.w*acc1.w;
    prt[(r0 + 2) * 17 + cg] = acc2.x*acc2.x + acc2.y*acc2.y + acc2.z*acc2.z + acc2.w*acc2.w;
    prt[(r0 + 3) * 17 + cg] = acc3.x*acc3.x + acc3.y*acc3.y + acc3.z*acc3.z + acc3.w*acc3.w;
    __syncthreads();
    if (tid < 64) {
      float s = 0.f;
#pragma unroll
      for (int t = 0; t < 16; ++t) s += prt[tid * 17 + t];
      inv64[tid] = 1.0f / fmaxf(sqrtf(s), 1e-12f);
    }
    __syncthreads();
    {
      float i0 = inv64[r0 + 0], i1 = inv64[r0 + 1];
      float i2 = inv64[r0 + 2], i3 = inv64[r0 + 3];
      float4 w0 = {acc0.x * i0, acc1.x * i1, acc2.x * i2, acc3.x * i3};
      float4 w1 = {acc0.y * i0, acc1.y * i1, acc2.y * i2, acc3.y * i3};
      float4 w2 = {acc0.z * i0, acc1.z * i1, acc2.z * i2, acc3.z * i3};
      float4 w3 = {acc0.w * i0, acc1.w * i1, acc2.w * i2, acc3.w * i3};
      *(float4*)&xT[(c0 + 0) * 68 + r0] = w0;
      *(float4*)&xT[(c0 + 1) * 68 + r0] = w1;
      *(float4*)&xT[(c0 + 2) * 68 + r0] = w2;
      *(float4*)&xT[(c0 + 3) * 68 + r0] = w3;
    }
    __syncthreads();
  }

  // pool
  {
    int k = tid & 63, half = tid >> 6;
    const float* xp = &xT[k * 68 + half * 16];
    float s = 0.f;
#pragma unroll
    for (int i = 0; i < 16; ++i) s += xp[i];
    red[half * 64 + k] = s;
  }
  __syncthreads();
  if (tid < 64) mol[tid] = red[tid] + red[64 + tid] + red[128 + tid] + red[192 + tid];
  __syncthreads();
  // fc: 256-wide, 4 threads per output, shuffle-4 reduce
  {
    int d = tid >> 2, q0 = (tid & 3) * 4;
    const float4* wr = (const float4*)(fc_w + d * 64 + q0 * 4);
    float p = 0.f;
#pragma unroll
    for (int i = 0; i < 4; ++i) {
      float4 w4 = wr[i];
      float4 m4 = *(const float4*)&mol[(q0 + i) * 4];
      p += w4.x * m4.x + w4.y * m4.y + w4.z * m4.z + w4.w * m4.w;
    }
    p += __shfl_xor(p, 1); p += __shfl_xor(p, 2);
    if ((tid & 3) == 0) {
      float a = p + fc_b[d];
      vloc[d] = a;
      vout[b * 64 + d] = a;
    }
  }
  __syncthreads();
  if (tid < 192) {   // layer-0 qkv
    const float4* wr = (const float4*)(qkv_w + tid * 64);
    float a = qkv_b[tid];
#pragma unroll
    for (int k4 = 0; k4 < 16; ++k4) {
      float4 w4 = wr[k4];
      float4 x4 = *(const float4*)&vloc[k4 * 4];
      a += w4.x * x4.x + w4.y * x4.y + w4.z * x4.z + w4.w * x4.w;
    }
    qqout[(size_t)b * 192 + tid] = a;
  }
}

// ======================================================================
// K2/K3: attention + FF for one layer; then next-layer qkv or head.
// grid=128 (token), block=512
// ======================================================================
template <bool LAST>
__global__ __launch_bounds__(512) void layer_kernel(
    const float* __restrict__ vin, const float* __restrict__ qq_in,
    const float* __restrict__ out_w, const float* __restrict__ out_b,
    const float* __restrict__ ln1_s, const float* __restrict__ ln1_b,
    const float* __restrict__ w1t, const float* __restrict__ ff1_b,
    const float* __restrict__ ff2_w, const float* __restrict__ ff2_b,
    const float* __restrict__ ln2_s, const float* __restrict__ ln2_b,
    const float* __restrict__ nqkv_w, const float* __restrict__ nqkv_b,
    float* __restrict__ qq_out,
    const float* __restrict__ Wout_w, const float* __restrict__ Wout_b,
    const float* __restrict__ Wprop_w, const float* __restrict__ Wprop_b,
    float* __restrict__ vout)
{
  __shared__ __align__(16) float qloc[192];
  __shared__ __align__(16) float Pl[4 * 132];
  __shared__ __align__(16) float cb[2048];
  __shared__ __align__(16) float redt[512];
  __shared__ __align__(16) float vloc[64];
  __shared__ __align__(16) float vloc2[64];
  __shared__ __align__(16) float osh[64];
  __shared__ __align__(16) float rres[64];
  __shared__ __align__(16) float ffp[64];
  __shared__ float w8b[8];

  const int b   = blockIdx.x;
  const int tid = threadIdx.x;

  if (tid < 64)  vloc[tid] = vin[b * 64 + tid];
  if (tid < 192) qloc[tid] = qq_in[(size_t)b * 192 + tid];
  __syncthreads();

  // ---- scores + softmax (no-max: |s|<~1, exp safe) ----
  {
    const int j = tid & 127, h = tid >> 7;
    const float4* qp = (const float4*)&qloc[h * 16];
    const float4* kp = (const float4*)(qq_in + (size_t)j * 192 + 64 + h * 16);
    float s = 0.f;
#pragma unroll
    for (int t = 0; t < 4; ++t) {
      float4 a4 = qp[t], b4 = kp[t];
      s += a4.x * b4.x + a4.y * b4.y + a4.z * b4.z + a4.w * b4.w;
    }
    float e = expf(s * 0.25f);   // 1/sqrt(16)
    float sm = e;
    for (int off = 32; off; off >>= 1) sm += __shfl_xor(sm, off);
    if ((tid & 63) == 0) w8b[tid >> 6] = sm;
    __syncthreads();
    Pl[h * 132 + j] = e / (w8b[2 * h] + w8b[2 * h + 1]);
  }
  __syncthreads();

  // ---- PV: thread = (d, j-chunk) ----
  {
    const int d = tid & 63, part = tid >> 6, h2 = d >> 4;
    float a = 0.f;
#pragma unroll
    for (int jj = 0; jj < 16; ++jj) {
      int j2 = part * 16 + jj;
      a += Pl[h2 * 132 + j2] * qq_in[(size_t)j2 * 192 + 128 + d];
    }
    redt[part * 64 + d] = a;
  }
  __syncthreads();
  if (tid < 64) {
    float o = 0.f;
#pragma unroll
    for (int p = 0; p < 8; ++p) o += redt[p * 64 + tid];
    osh[tid] = o;
  }
  __syncthreads();

  // ---- out-proj: 512-wide, shuffle-8 ----
  {
    int d = tid >> 3, q0 = (tid & 7) * 2;
    const float4* wr = (const float4*)(out_w + d * 64 + q0 * 4);
    float p = 0.f;
#pragma unroll
    for (int i = 0; i < 2; ++i) {
      float4 w4 = wr[i];
      float4 o4 = *(const float4*)&osh[(q0 + i) * 4];
      p += w4.x * o4.x + w4.y * o4.y + w4.z * o4.z + w4.w * o4.w;
    }
    p += __shfl_xor(p, 1); p += __shfl_xor(p, 2); p += __shfl_xor(p, 4);
    if ((tid & 7) == 0) rres[d] = p;
  }
  __syncthreads();

  // ---- residual + LN1 ----
  if (tid < 64) {
    const int d = tid;
    float r = vloc[d] + rres[d] + out_b[d];
    float mu = r;
    for (int off = 32; off; off >>= 1) mu += __shfl_xor(mu, off);
    mu *= (1.0f / 64.0f);
    float df = r - mu;
    float var = df * df;
    for (int off = 32; off; off >>= 1) var += __shfl_xor(var, off);
    var *= (1.0f / 64.0f);
    vloc2[d] = df / sqrtf(var + 1e-5f) * ln1_s[d] + ln1_b[d];
  }
  __syncthreads();

  // ---- FF phase 1: f32 transposed w1 (k-major), coalesced ----
  {
    const float4* wt = (const float4*)w1t;   // [64][512] float4 rows
    float4 a0 = {0.f, 0.f, 0.f, 0.f}, a1 = {0.f, 0.f, 0.f, 0.f};
#pragma unroll 8
    for (int k = 0; k < 64; k += 2) {
      float v0 = vloc2[k], v1 = vloc2[k + 1];
      float4 w0 = wt[(size_t)k * 512 + tid];
      float4 w1v = wt[(size_t)(k + 1) * 512 + tid];
      a0.x += v0 * w0.x; a0.y += v0 * w0.y; a0.z += v0 * w0.z; a0.w += v0 * w0.w;
      a1.x += v1 * w1v.x; a1.y += v1 * w1v.y; a1.z += v1 * w1v.z; a1.w += v1 * w1v.w;
    }
    const int j0 = tid * 4;
    float4 bb = *(const float4*)&ff1_b[j0];
    float4 r;
    r.x = fmaxf(a0.x + a1.x + bb.x, 0.f);
    r.y = fmaxf(a0.y + a1.y + bb.y, 0.f);
    r.z = fmaxf(a0.z + a1.z + bb.z, 0.f);
    r.w = fmaxf(a0.w + a1.w + bb.w, 0.f);
    *(float4*)&cb[j0] = r;
  }
  __syncthreads();

  // ---- FF phase 2: wave owns 8 rows, coalesced ----
  {
    const int w = tid >> 6, lane = tid & 63;
    const float4* w2f = (const float4*)ff2_w;
    const float4* cbf = (const float4*)cb;
#pragma unroll
    for (int rr = 0; rr < 8; ++rr) {
      int d = w * 8 + rr;
      float p = 0.f;
#pragma unroll
      for (int it = 0; it < 8; ++it) {
        int f = it * 64 + lane;
        float4 wv = w2f[d * 512 + f];
        float4 cv = cbf[f];
        p += wv.x * cv.x + wv.y * cv.y + wv.z * cv.z + wv.w * cv.w;
      }
      for (int off = 32; off; off >>= 1) p += __shfl_xor(p, off);
      if (lane == 0) ffp[d] = p;
    }
  }
  __syncthreads();

  // ---- residual + LN2 -> vloc ----
  if (tid < 64) {
    const int d = tid;
    float r = vloc2[d] + ffp[d] + ff2_b[d];
    float mu = r;
    for (int off = 32; off; off >>= 1) mu += __shfl_xor(mu, off);
    mu *= (1.0f / 64.0f);
    float df = r - mu;
    float var = df * df;
    for (int off = 32; off; off >>= 1) var += __shfl_xor(var, off);
    var *= (1.0f / 64.0f);
    vloc[d] = df / sqrtf(var + 1e-5f) * ln2_s[d] + ln2_b[d];
  }
  __syncthreads();

  if (!LAST) {
    if (tid < 64) vout[b * 64 + tid] = vloc[tid];
    // next-layer qkv: 384-wide, shuffle-2
    if (tid < 384) {
      int o = tid >> 1, q0 = (tid & 1) * 32;
      const float4* wr = (const float4*)(nqkv_w + o * 64 + q0);
      float p = 0.f;
#pragma unroll
      for (int k4 = 0; k4 < 8; ++k4) {
        float4 w4 = wr[k4];
        float4 x4 = *(const float4*)&vloc[q0 + k4 * 4];
        p += w4.x * x4.x + w4.y * x4.y + w4.z * x4.z + w4.w * x4.w;
      }
      p += __shfl_xor(p, 1);
      if ((tid & 1) == 0) qq_out[(size_t)b * 192 + o] = p + nqkv_b[o];
    }
  } else {
    // output head: 512-wide shuffle-8 for both 64x64 layers
    {
      int d = tid >> 3, q0 = (tid & 7) * 2;
      const float4* wr = (const float4*)(Wout_w + d * 64 + q0 * 4);
      float p = 0.f;
#pragma unroll
      for (int i = 0; i < 2; ++i) {
        float4 w4 = wr[i];
        float4 v4 = *(const float4*)&vloc[(q0 + i) * 4];
        p += w4.x * v4.x + w4.y * v4.y + w4.z * v4.z + w4.w * v4.w;
      }
      p += __shfl_xor(p, 1); p += __shfl_xor(p, 2); p += __shfl_xor(p, 4);
      if ((tid & 7) == 0) redt[d] = fmaxf(p + Wout_b[d], 0.f);
    }
    __syncthreads();
    {
      int d = tid >> 3, q0 = (tid & 7) * 2;
      const float4* wr = (const float4*)(Wout_w + 4096 + d * 64 + q0 * 4);
      float p = 0.f;
#pragma unroll
      for (int i = 0; i < 2; ++i) {
        float4 w4 = wr[i];
        float4 v4 = *(const float4*)&redt[(q0 + i) * 4];
        p += w4.x * v4.x + w4.y * v4.y + w4.z * v4.z + w4.w * v4.w;
      }
      p += __shfl_xor(p, 1); p += __shfl_xor(p, 2); p += __shfl_xor(p, 4);
      if ((tid & 7) == 0) redt[64 + d] = fmaxf(p + Wout_b[64 + d], 0.f);
    }
    __syncthreads();
    if (tid < 2) {
      float a = Wprop_b[tid];
      const float* wr = Wprop_w + tid * 64;
#pragma unroll 8
      for (int c = 0; c < 64; ++c) a += redt[64 + c] * wr[c];
      vout[b * 2 + tid] = a;
    }
  }
}

// ======================================================================
extern "C" void kernel_launch(void* const* d_in, const int* in_sizes, int n_in,
                              void* d_out, int out_size, void* d_ws, size_t ws_size,
                              hipStream_t stream) {
  const int*   fp      = (const int*)  d_in[0];
  const float* Aadj    = (const float*)d_in[1];
  const float* embed   = (const float*)d_in[2];
  const float* Wfp     = (const float*)d_in[3];
  const float* bfp     = (const float*)d_in[4];
  const float* fc_w    = (const float*)d_in[5];
  const float* fc_b    = (const float*)d_in[6];
  const float* qkv_w   = (const float*)d_in[7];
  const float* qkv_b   = (const float*)d_in[8];
  const float* out_w   = (const float*)d_in[9];
  const float* out_b   = (const float*)d_in[10];
  const float* ln1_s   = (const float*)d_in[11];
  const float* ln1_b   = (const float*)d_in[12];
  const float* ff1_w   = (const float*)d_in[13];
  const float* ff1_b   = (const float*)d_in[14];
  const float* ff2_w   = (const float*)d_in[15];
  const float* ff2_b   = (const float*)d_in[16];
  const float* ln2_s   = (const float*)d_in[17];
  const float* ln2_b   = (const float*)d_in[18];
  const float* Wout_w  = (const float*)d_in[19];
  const float* Wout_b  = (const float*)d_in[20];
  const float* Wprop_w = (const float*)d_in[21];
  const float* Wprop_b = (const float*)d_in[22];
  float* out = (float*)d_out;

  float* ws  = (float*)d_ws;
  float* v0  = ws;             // [128][64]
  float* v1  = ws + 8192;      // [128][64]
  float* qq0 = ws + 16384;     // [128][192]
  float* qq1 = ws + 40960;     // [128][192]
  float* wT1 = ws + 65536;     // 2 x [64][2048] f32 (k-major)

  gnn_kernel<<<dim3(NB + 64), dim3(256), 0, stream>>>(
      fp, Aadj, embed, Wfp, bfp, fc_w, fc_b, qkv_w, qkv_b,
      ff1_w, wT1, v0, qq0);

  layer_kernel<false><<<dim3(NB), dim3(512), 0, stream>>>(
      v0, qq0, out_w, out_b, ln1_s, ln1_b,
      wT1, ff1_b, ff2_w, ff2_b, ln2_s, ln2_b,
      qkv_w + 12288, qkv_b + 192, qq1,
      nullptr, nullptr, nullptr, nullptr, v1);

  layer_kernel<true><<<dim3(NB), dim3(512), 0, stream>>>(
      v1, qq1, out_w + 4096, out_b + 64, ln1_s + 64, ln1_b + 64,
      wT1 + 131072, ff1_b + 2048, ff2_w + 131072, ff2_b + 64,
      ln2_s + 64, ln2_b + 64,
      nullptr, nullptr, nullptr,
      Wout_w, Wout_b, Wprop_w, Wprop_b, out);
}

// Round 9
// 50.023 us; speedup vs baseline: 1.7151x; 1.2881x over previous
//
#include <hip/hip_runtime.h>
#include <cstddef>

#define NB 128   // #molecules / tokens

typedef short  bf16x8 __attribute__((ext_vector_type(8)));
typedef float  f32x4  __attribute__((ext_vector_type(4)));

// bf16 RNE pack (result in low 16 bits)
__device__ __forceinline__ unsigned int f2bf(float x) {
  unsigned int u = __float_as_uint(x);
  u = (u + 0x7FFFu + ((u >> 16) & 1u)) >> 16;
  return u;
}

// ======================================================================
// K1: blocks 0..127: MFMA-bf16 GNN + pool + fc + qkv(layer0).
//     blocks 128..191: transpose ff1_w -> wT1 (f32, k-major).
// block=256 (4 waves; wave = row-tile of 16 atoms).
// Hazard-free LDS plan: ping-pong x (xA/xB), W0..W2 staged once
// (read-only after initial sync), hT double-barriered, unconditional
// end-of-layer barrier.
// ======================================================================
__global__ __launch_bounds__(256) void gnn_kernel(
    const int* __restrict__ fp, const float* __restrict__ Aadj,
    const float* __restrict__ embed, const float* __restrict__ Wfp,
    const float* __restrict__ bfp, const float* __restrict__ fc_w,
    const float* __restrict__ fc_b,
    const float* __restrict__ qkv_w, const float* __restrict__ qkv_b,
    const float* __restrict__ ff1_w, float* __restrict__ wT1,
    float* __restrict__ vout, float* __restrict__ qqout)
{
  // 7 bf16 tiles [64][72] (xA, xB, hT, A, W0, W1, W2) + f32 scratch
  __shared__ __align__(16) unsigned char smemraw[7 * 9216 + 1536];
  unsigned short* xA  = (unsigned short*)smemraw;
  unsigned short* xB  = xA + 4608;
  unsigned short* hT  = xB + 4608;
  unsigned short* Ab  = hT + 4608;
  unsigned short* Ws0 = Ab + 4608;                  // 3 x 4608 ushorts
  float* prt  = (float*)(smemraw + 7 * 9216);       // [4][64]
  float* mol  = prt + 256;
  float* vloc = mol + 64;

  const int bid = blockIdx.x;
  const int tid = threadIdx.x;

  // ---------------- transpose utility blocks ----------------
  if (bid >= NB) {
    float* xT = (float*)smemraw;       // [64][68] f32 scratch
    const int t = bid - NB;            // 0..63
    const int l = t >> 5, j0 = (t & 31) * 64;
    const float* src = ff1_w + (size_t)l * 131072;
    float*       dst = wT1  + (size_t)l * 131072;
#pragma unroll
    for (int q = 0; q < 4; ++q) {
      int jr = (tid >> 4) + 16 * q, kq = tid & 15;
      float4 vv = *(const float4*)(src + (size_t)(j0 + jr) * 64 + kq * 4);
      *(float4*)&xT[jr * 68 + kq * 4] = vv;
    }
    __syncthreads();
#pragma unroll
    for (int q = 0; q < 4; ++q) {
      int kr = (tid >> 4) + 16 * q, jq = tid & 15;
      float4 ov;
      ov.x = xT[(jq * 4 + 0) * 68 + kr];
      ov.y = xT[(jq * 4 + 1) * 68 + kr];
      ov.z = xT[(jq * 4 + 2) * 68 + kr];
      ov.w = xT[(jq * 4 + 3) * 68 + kr];
      *(float4*)(dst + (size_t)kr * 2048 + j0 + jq * 4) = ov;
    }
    return;
  }

  // ---------------- GNN blocks ----------------
  const int b   = bid;
  const int rt  = tid >> 6;          // wave id = row-tile (atoms 16rt..16rt+15)
  const int ln  = tid & 63;
  const int r16 = ln & 15;           // fragment row/col index within tile
  const int kb  = ln >> 4;           // k-block (0..3)

  // ---- stage EVERYTHING once: x0, A, W0..W2 (then one barrier) ----
  for (int idx = tid; idx < 1024; idx += 256) {     // x0 [atom][k]
    int r = idx >> 4, q = (idx & 15) * 4;
    float4 v = *(const float4*)(embed + (size_t)fp[b * 64 + r] * 64 + q);
    uint2 o;
    o.x = f2bf(v.x) | (f2bf(v.y) << 16);
    o.y = f2bf(v.z) | (f2bf(v.w) << 16);
    *(uint2*)&xA[r * 72 + q] = o;
  }
  for (int idx = tid; idx < 1024; idx += 256) {     // A [i][j] (0/1 exact)
    int r = idx >> 4, q = (idx & 15) * 4;
    float4 v = *(const float4*)(Aadj + (size_t)(b * 64 + r) * 8192 + b * 64 + q);
    uint2 o;
    o.x = f2bf(v.x) | (f2bf(v.y) << 16);
    o.y = f2bf(v.z) | (f2bf(v.w) << 16);
    *(uint2*)&Ab[r * 72 + q] = o;
  }
  for (int idx = tid; idx < 3072; idx += 256) {     // W_l [o][k], l=0..2
    int l = idx >> 10, rem = idx & 1023;
    int o = rem >> 4, q = (rem & 15) * 4;
    float4 v = *(const float4*)(Wfp + l * 4096 + o * 64 + q);
    uint2 ov;
    ov.x = f2bf(v.x) | (f2bf(v.y) << 16);
    ov.y = f2bf(v.z) | (f2bf(v.w) << 16);
    *(uint2*)&Ws0[l * 4608 + o * 72 + q] = ov;
  }
  __syncthreads();   // all staged buffers visible; W/A read-only hereafter

  unsigned short* xcur = xA;
  unsigned short* xnxt = xB;
  f32x4 hs[4];       // final-layer normalized fragments survive for pooling

  for (int l = 0; l < 3; ++l) {
    const unsigned short* Wl = Ws0 + l * 4608;

    // ---- phase 1: h = relu(x @ W^T + b) via MFMA; write hT (own cols) ----
    bf16x8 ax0 = *(const bf16x8*)&xcur[(16 * rt + r16) * 72 + kb * 8];
    bf16x8 ax1 = *(const bf16x8*)&xcur[(16 * rt + r16) * 72 + 32 + kb * 8];
    f32x4 hacc[4];
#pragma unroll
    for (int ct = 0; ct < 4; ++ct) {
      const int o = 16 * ct + r16;
      bf16x8 b0 = *(const bf16x8*)&Wl[o * 72 + kb * 8];
      bf16x8 b1 = *(const bf16x8*)&Wl[o * 72 + 32 + kb * 8];
      float bias = bfp[l * 64 + o];
      f32x4 acc = {bias, bias, bias, bias};
      acc = __builtin_amdgcn_mfma_f32_16x16x32_bf16(ax0, b0, acc, 0, 0, 0);
      acc = __builtin_amdgcn_mfma_f32_16x16x32_bf16(ax1, b1, acc, 0, 0, 0);
      acc[0] = fmaxf(acc[0], 0.f); acc[1] = fmaxf(acc[1], 0.f);
      acc[2] = fmaxf(acc[2], 0.f); acc[3] = fmaxf(acc[3], 0.f);
      hacc[ct] = acc;
      uint2 ov;
      ov.x = f2bf(acc[0]) | (f2bf(acc[1]) << 16);
      ov.y = f2bf(acc[2]) | (f2bf(acc[3]) << 16);
      *(uint2*)&hT[o * 72 + 16 * rt + kb * 4] = ov;
    }
    __syncthreads();   // hT fully written

    // ---- phase 2: hs = h + A @ h via MFMA (C-init = f32 h fragments) ----
    bf16x8 aa0 = *(const bf16x8*)&Ab[(16 * rt + r16) * 72 + kb * 8];
    bf16x8 aa1 = *(const bf16x8*)&Ab[(16 * rt + r16) * 72 + 32 + kb * 8];
#pragma unroll
    for (int ct = 0; ct < 4; ++ct) {
      const int o = 16 * ct + r16;
      bf16x8 b0 = *(const bf16x8*)&hT[o * 72 + kb * 8];
      bf16x8 b1 = *(const bf16x8*)&hT[o * 72 + 32 + kb * 8];
      f32x4 acc = hacc[ct];
      acc = __builtin_amdgcn_mfma_f32_16x16x32_bf16(aa0, b0, acc, 0, 0, 0);
      acc = __builtin_amdgcn_mfma_f32_16x16x32_bf16(aa1, b1, acc, 0, 0, 0);
      hs[ct] = acc;
    }

    // ---- row L2 norm on fragments (lane: rows 16rt+4kb+j, col 16ct+r16) ----
    float4 ss;
    ss.x = hs[0][0]*hs[0][0] + hs[1][0]*hs[1][0] + hs[2][0]*hs[2][0] + hs[3][0]*hs[3][0];
    ss.y = hs[0][1]*hs[0][1] + hs[1][1]*hs[1][1] + hs[2][1]*hs[2][1] + hs[3][1]*hs[3][1];
    ss.z = hs[0][2]*hs[0][2] + hs[1][2]*hs[1][2] + hs[2][2]*hs[2][2] + hs[3][2]*hs[3][2];
    ss.w = hs[0][3]*hs[0][3] + hs[1][3]*hs[1][3] + hs[2][3]*hs[2][3] + hs[3][3]*hs[3][3];
#pragma unroll
    for (int m = 1; m <= 8; m <<= 1) {   // reduce over the 16 r16-lanes (cols)
      ss.x += __shfl_xor(ss.x, m);
      ss.y += __shfl_xor(ss.y, m);
      ss.z += __shfl_xor(ss.z, m);
      ss.w += __shfl_xor(ss.w, m);
    }
    float4 inv;
    inv.x = 1.0f / fmaxf(sqrtf(ss.x), 1e-12f);
    inv.y = 1.0f / fmaxf(sqrtf(ss.y), 1e-12f);
    inv.z = 1.0f / fmaxf(sqrtf(ss.z), 1e-12f);
    inv.w = 1.0f / fmaxf(sqrtf(ss.w), 1e-12f);
#pragma unroll
    for (int ct = 0; ct < 4; ++ct) {
      hs[ct][0] *= inv.x; hs[ct][1] *= inv.y;
      hs[ct][2] *= inv.z; hs[ct][3] *= inv.w;
    }

    if (l < 2) {
      // write x_{l+1} into the OTHER buffer (wave-local rows, scattered u16)
#pragma unroll
      for (int ct = 0; ct < 4; ++ct) {
        const int col = 16 * ct + r16;
        xnxt[(16 * rt + kb * 4 + 0) * 72 + col] = (unsigned short)f2bf(hs[ct][0]);
        xnxt[(16 * rt + kb * 4 + 1) * 72 + col] = (unsigned short)f2bf(hs[ct][1]);
        xnxt[(16 * rt + kb * 4 + 2) * 72 + col] = (unsigned short)f2bf(hs[ct][2]);
        xnxt[(16 * rt + kb * 4 + 3) * 72 + col] = (unsigned short)f2bf(hs[ct][3]);
      }
    }
    __syncthreads();   // UNCONDITIONAL end-of-layer barrier (hT reuse fence)

    unsigned short* tmp = xcur; xcur = xnxt; xnxt = tmp;
  }

  // ---- pool from final fragments: mol[k] = sum_atoms x[.,k] ----
  {
    float psum[4];
#pragma unroll
    for (int ct = 0; ct < 4; ++ct)
      psum[ct] = hs[ct][0] + hs[ct][1] + hs[ct][2] + hs[ct][3];
#pragma unroll
    for (int ct = 0; ct < 4; ++ct) {   // reduce across kb groups (row blocks)
      psum[ct] += __shfl_xor(psum[ct], 16);
      psum[ct] += __shfl_xor(psum[ct], 32);
    }
    if (ln < 16) {
#pragma unroll
      for (int ct = 0; ct < 4; ++ct)
        prt[rt * 64 + 16 * ct + r16] = psum[ct];
    }
  }
  __syncthreads();
  if (tid < 64)
    mol[tid] = prt[tid] + prt[64 + tid] + prt[128 + tid] + prt[192 + tid];
  __syncthreads();
  // fc: 256-wide, shuffle-4
  {
    int d = tid >> 2, q0 = (tid & 3) * 4;
    const float4* wr = (const float4*)(fc_w + d * 64 + q0 * 4);
    float p = 0.f;
#pragma unroll
    for (int i = 0; i < 4; ++i) {
      float4 w4 = wr[i];
      float4 m4 = *(const float4*)&mol[(q0 + i) * 4];
      p += w4.x * m4.x + w4.y * m4.y + w4.z * m4.z + w4.w * m4.w;
    }
    p += __shfl_xor(p, 1); p += __shfl_xor(p, 2);
    if ((tid & 3) == 0) {
      float a = p + fc_b[d];
      vloc[d] = a;
      vout[b * 64 + d] = a;
    }
  }
  __syncthreads();
  if (tid < 192) {   // layer-0 qkv
    const float4* wr = (const float4*)(qkv_w + tid * 64);
    float a = qkv_b[tid];
#pragma unroll
    for (int k4 = 0; k4 < 16; ++k4) {
      float4 w4 = wr[k4];
      float4 x4 = *(const float4*)&vloc[k4 * 4];
      a += w4.x * x4.x + w4.y * x4.y + w4.z * x4.z + w4.w * x4.w;
    }
    qqout[(size_t)b * 192 + tid] = a;
  }
}

// ======================================================================
// K2/K3: attention + FF for one layer; then next-layer qkv or head.
// grid=128 (token), block=512.  (Byte-identical to R7 — proven
// post-timing-deterministic.)
// ======================================================================
template <bool LAST>
__global__ __launch_bounds__(512) void layer_kernel(
    const float* __restrict__ vin, const float* __restrict__ qq_in,
    const float* __restrict__ out_w, const float* __restrict__ out_b,
    const float* __restrict__ ln1_s, const float* __restrict__ ln1_b,
    const float* __restrict__ w1t, const float* __restrict__ ff1_b,
    const float* __restrict__ ff2_w, const float* __restrict__ ff2_b,
    const float* __restrict__ ln2_s, const float* __restrict__ ln2_b,
    const float* __restrict__ nqkv_w, const float* __restrict__ nqkv_b,
    float* __restrict__ qq_out,
    const float* __restrict__ Wout_w, const float* __restrict__ Wout_b,
    const float* __restrict__ Wprop_w, const float* __restrict__ Wprop_b,
    float* __restrict__ vout)
{
  __shared__ __align__(16) float qloc[192];
  __shared__ __align__(16) float Pl[4 * 132];
  __shared__ __align__(16) float cb[2048];
  __shared__ __align__(16) float redt[512];
  __shared__ __align__(16) float vloc[64];
  __shared__ __align__(16) float vloc2[64];
  __shared__ __align__(16) float osh[64];
  __shared__ __align__(16) float rres[64];
  __shared__ __align__(16) float ffp[64];
  __shared__ float w8b[8];

  const int b   = blockIdx.x;
  const int tid = threadIdx.x;

  if (tid < 64)  vloc[tid] = vin[b * 64 + tid];
  if (tid < 192) qloc[tid] = qq_in[(size_t)b * 192 + tid];
  __syncthreads();

  // ---- scores + softmax (no-max: |s| tiny, exp safe) ----
  {
    const int j = tid & 127, h = tid >> 7;
    const float4* qp = (const float4*)&qloc[h * 16];
    const float4* kp = (const float4*)(qq_in + (size_t)j * 192 + 64 + h * 16);
    float s = 0.f;
#pragma unroll
    for (int t = 0; t < 4; ++t) {
      float4 a4 = qp[t], b4 = kp[t];
      s += a4.x * b4.x + a4.y * b4.y + a4.z * b4.z + a4.w * b4.w;
    }
    float e = expf(s * 0.25f);
    float sm = e;
    for (int off = 32; off; off >>= 1) sm += __shfl_xor(sm, off);
    if ((tid & 63) == 0) w8b[tid >> 6] = sm;
    __syncthreads();
    Pl[h * 132 + j] = e / (w8b[2 * h] + w8b[2 * h + 1]);
  }
  __syncthreads();

  // ---- PV ----
  {
    const int d = tid & 63, part = tid >> 6, h2 = d >> 4;
    float a = 0.f;
#pragma unroll
    for (int jj = 0; jj < 16; ++jj) {
      int j2 = part * 16 + jj;
      a += Pl[h2 * 132 + j2] * qq_in[(size_t)j2 * 192 + 128 + d];
    }
    redt[part * 64 + d] = a;
  }
  __syncthreads();
  if (tid < 64) {
    float o = 0.f;
#pragma unroll
    for (int p = 0; p < 8; ++p) o += redt[p * 64 + tid];
    osh[tid] = o;
  }
  __syncthreads();

  // ---- out-proj: 512-wide, shuffle-8 ----
  {
    int d = tid >> 3, q0 = (tid & 7) * 2;
    const float4* wr = (const float4*)(out_w + d * 64 + q0 * 4);
    float p = 0.f;
#pragma unroll
    for (int i = 0; i < 2; ++i) {
      float4 w4 = wr[i];
      float4 o4 = *(const float4*)&osh[(q0 + i) * 4];
      p += w4.x * o4.x + w4.y * o4.y + w4.z * o4.z + w4.w * o4.w;
    }
    p += __shfl_xor(p, 1); p += __shfl_xor(p, 2); p += __shfl_xor(p, 4);
    if ((tid & 7) == 0) rres[d] = p;
  }
  __syncthreads();

  // ---- residual + LN1 ----
  if (tid < 64) {
    const int d = tid;
    float r = vloc[d] + rres[d] + out_b[d];
    float mu = r;
    for (int off = 32; off; off >>= 1) mu += __shfl_xor(mu, off);
    mu *= (1.0f / 64.0f);
    float df = r - mu;
    float var = df * df;
    for (int off = 32; off; off >>= 1) var += __shfl_xor(var, off);
    var *= (1.0f / 64.0f);
    vloc2[d] = df / sqrtf(var + 1e-5f) * ln1_s[d] + ln1_b[d];
  }
  __syncthreads();

  // ---- FF phase 1: f32 transposed w1 (k-major), coalesced ----
  {
    const float4* wt = (const float4*)w1t;
    float4 a0 = {0.f, 0.f, 0.f, 0.f}, a1 = {0.f, 0.f, 0.f, 0.f};
#pragma unroll 8
    for (int k = 0; k < 64; k += 2) {
      float v0 = vloc2[k], v1 = vloc2[k + 1];
      float4 w0 = wt[(size_t)k * 512 + tid];
      float4 w1v = wt[(size_t)(k + 1) * 512 + tid];
      a0.x += v0 * w0.x; a0.y += v0 * w0.y; a0.z += v0 * w0.z; a0.w += v0 * w0.w;
      a1.x += v1 * w1v.x; a1.y += v1 * w1v.y; a1.z += v1 * w1v.z; a1.w += v1 * w1v.w;
    }
    const int j0 = tid * 4;
    float4 bb = *(const float4*)&ff1_b[j0];
    float4 r;
    r.x = fmaxf(a0.x + a1.x + bb.x, 0.f);
    r.y = fmaxf(a0.y + a1.y + bb.y, 0.f);
    r.z = fmaxf(a0.z + a1.z + bb.z, 0.f);
    r.w = fmaxf(a0.w + a1.w + bb.w, 0.f);
    *(float4*)&cb[j0] = r;
  }
  __syncthreads();

  // ---- FF phase 2: wave owns 8 rows, coalesced ----
  {
    const int w = tid >> 6, lane = tid & 63;
    const float4* w2f = (const float4*)ff2_w;
    const float4* cbf = (const float4*)cb;
#pragma unroll
    for (int rr = 0; rr < 8; ++rr) {
      int d = w * 8 + rr;
      float p = 0.f;
#pragma unroll
      for (int it = 0; it < 8; ++it) {
        int f = it * 64 + lane;
        float4 wv = w2f[d * 512 + f];
        float4 cv = cbf[f];
        p += wv.x * cv.x + wv.y * cv.y + wv.z * cv.z + wv.w * cv.w;
      }
      for (int off = 32; off; off >>= 1) p += __shfl_xor(p, off);
      if (lane == 0) ffp[d] = p;
    }
  }
  __syncthreads();

  // ---- residual + LN2 -> vloc ----
  if (tid < 64) {
    const int d = tid;
    float r = vloc2[d] + ffp[d] + ff2_b[d];
    float mu = r;
    for (int off = 32; off; off >>= 1) mu += __shfl_xor(mu, off);
    mu *= (1.0f / 64.0f);
    float df = r - mu;
    float var = df * df;
    for (int off = 32; off; off >>= 1) var += __shfl_xor(var, off);
    var *= (1.0f / 64.0f);
    vloc[d] = df / sqrtf(var + 1e-5f) * ln2_s[d] + ln2_b[d];
  }
  __syncthreads();

  if (!LAST) {
    if (tid < 64) vout[b * 64 + tid] = vloc[tid];
    if (tid < 384) {   // next-layer qkv: 384-wide, shuffle-2
      int o = tid >> 1, q0 = (tid & 1) * 32;
      const float4* wr = (const float4*)(nqkv_w + o * 64 + q0);
      float p = 0.f;
#pragma unroll
      for (int k4 = 0; k4 < 8; ++k4) {
        float4 w4 = wr[k4];
        float4 x4 = *(const float4*)&vloc[q0 + k4 * 4];
        p += w4.x * x4.x + w4.y * x4.y + w4.z * x4.z + w4.w * x4.w;
      }
      p += __shfl_xor(p, 1);
      if ((tid & 1) == 0) qq_out[(size_t)b * 192 + o] = p + nqkv_b[o];
    }
  } else {
    // output head: 512-wide shuffle-8 for both 64x64 layers
    {
      int d = tid >> 3, q0 = (tid & 7) * 2;
      const float4* wr = (const float4*)(Wout_w + d * 64 + q0 * 4);
      float p = 0.f;
#pragma unroll
      for (int i = 0; i < 2; ++i) {
        float4 w4 = wr[i];
        float4 v4 = *(const float4*)&vloc[(q0 + i) * 4];
        p += w4.x * v4.x + w4.y * v4.y + w4.z * v4.z + w4.w * v4.w;
      }
      p += __shfl_xor(p, 1); p += __shfl_xor(p, 2); p += __shfl_xor(p, 4);
      if ((tid & 7) == 0) redt[d] = fmaxf(p + Wout_b[d], 0.f);
    }
    __syncthreads();
    {
      int d = tid >> 3, q0 = (tid & 7) * 2;
      const float4* wr = (const float4*)(Wout_w + 4096 + d * 64 + q0 * 4);
      float p = 0.f;
#pragma unroll
      for (int i = 0; i < 2; ++i) {
        float4 w4 = wr[i];
        float4 v4 = *(const float4*)&redt[(q0 + i) * 4];
        p += w4.x * v4.x + w4.y * v4.y + w4.z * v4.z + w4.w * v4.w;
      }
      p += __shfl_xor(p, 1); p += __shfl_xor(p, 2); p += __shfl_xor(p, 4);
      if ((tid & 7) == 0) redt[64 + d] = fmaxf(p + Wout_b[64 + d], 0.f);
    }
    __syncthreads();
    if (tid < 2) {
      float a = Wprop_b[tid];
      const float* wr = Wprop_w + tid * 64;
#pragma unroll 8
      for (int c = 0; c < 64; ++c) a += redt[64 + c] * wr[c];
      vout[b * 2 + tid] = a;
    }
  }
}

// ======================================================================
extern "C" void kernel_launch(void* const* d_in, const int* in_sizes, int n_in,
                              void* d_out, int out_size, void* d_ws, size_t ws_size,
                              hipStream_t stream) {
  const int*   fp      = (const int*)  d_in[0];
  const float* Aadj    = (const float*)d_in[1];
  const float* embed   = (const float*)d_in[2];
  const float* Wfp     = (const float*)d_in[3];
  const float* bfp     = (const float*)d_in[4];
  const float* fc_w    = (const float*)d_in[5];
  const float* fc_b    = (const float*)d_in[6];
  const float* qkv_w   = (const float*)d_in[7];
  const float* qkv_b   = (const float*)d_in[8];
  const float* out_w   = (const float*)d_in[9];
  const float* out_b   = (const float*)d_in[10];
  const float* ln1_s   = (const float*)d_in[11];
  const float* ln1_b   = (const float*)d_in[12];
  const float* ff1_w   = (const float*)d_in[13];
  const float* ff1_b   = (const float*)d_in[14];
  const float* ff2_w   = (const float*)d_in[15];
  const float* ff2_b   = (const float*)d_in[16];
  const float* ln2_s   = (const float*)d_in[17];
  const float* ln2_b   = (const float*)d_in[18];
  const float* Wout_w  = (const float*)d_in[19];
  const float* Wout_b  = (const float*)d_in[20];
  const float* Wprop_w = (const float*)d_in[21];
  const float* Wprop_b = (const float*)d_in[22];
  float* out = (float*)d_out;

  float* ws  = (float*)d_ws;
  float* v0  = ws;             // [128][64]
  float* v1  = ws + 8192;      // [128][64]
  float* qq0 = ws + 16384;     // [128][192]
  float* qq1 = ws + 40960;     // [128][192]
  float* wT1 = ws + 65536;     // 2 x [64][2048] f32 (k-major)

  gnn_kernel<<<dim3(NB + 64), dim3(256), 0, stream>>>(
      fp, Aadj, embed, Wfp, bfp, fc_w, fc_b, qkv_w, qkv_b,
      ff1_w, wT1, v0, qq0);

  layer_kernel<false><<<dim3(NB), dim3(512), 0, stream>>>(
      v0, qq0, out_w, out_b, ln1_s, ln1_b,
      wT1, ff1_b, ff2_w, ff2_b, ln2_s, ln2_b,
      qkv_w + 12288, qkv_b + 192, qq1,
      nullptr, nullptr, nullptr, nullptr, v1);

  layer_kernel<true><<<dim3(NB), dim3(512), 0, stream>>>(
      v1, qq1, out_w + 4096, out_b + 64, ln1_s + 64, ln1_b + 64,
      wT1 + 131072, ff1_b + 2048, ff2_w + 131072, ff2_b + 64,
      ln2_s + 64, ln2_b + 64,
      nullptr, nullptr, nullptr,
      Wout_w, Wout_b, Wprop_w, Wprop_b, out);
}